// Round 7
// baseline (118.958 us; speedup 1.0000x reference)
//
#include <hip/hip_runtime.h>

// Problem constants
#define B_   8
#define TE_  256
#define TD_  256
#define D_   256
#define U_   256

// Workspace layout (float offsets). ~4.2 MB.
// EeT is stored INTERLEAVED: EeT[b][u4][t][j] = exp2(2log2e*ae[b,t,4*u4+j])
// so the K24 u-loop reads one float4 (4 u-values) per lane per iteration.
#define EET_OFF   0        // (B, U/4, TE, 4)
#define ED_OFF    524288   // (B, TD, U)  Ed = exp2(2log2e * de@w_de), row-major
#define MAXMU_OFF 1048576  // (B, TD)     row max of mu'

__device__ __forceinline__ float fexp2(float x) {
#if __has_builtin(__builtin_amdgcn_exp2f)
  return __builtin_amdgcn_exp2f(x);
#else
  return exp2f(x);
#endif
}
__device__ __forceinline__ float frcp(float x) {
#if __has_builtin(__builtin_amdgcn_rcpf)
  return __builtin_amdgcn_rcpf(x);
#else
  return 1.0f / x;
#endif
}

#define LOG2E_F 1.4426950408889634f
#define TWO_LOG2E_F 2.8853900817779268f

// ---------------------------------------------------------------------------
// K1 v4 (IDENTICAL to R6): 64 rows x 32 U-cols, 512 threads, 2x2 microtile,
// grid (8, 32, 2) = 512 blocks. W-panel staged to LDS once, barrier-free
// k-loop, A-loads lane-dedup'd.
// ---------------------------------------------------------------------------
__global__ __launch_bounds__(512) void coatt_k1_proj(
    const float* __restrict__ en, const float* __restrict__ de,
    const float* __restrict__ w_en, const float* __restrict__ w_de,
    float* __restrict__ eet, float* __restrict__ edp) {
  const int which = blockIdx.z;  // 0: en->EeT (interleaved), 1: de->Ed (direct)
  const float* __restrict__ A = which ? de : en;     // (2048, 256)
  const float* __restrict__ W = which ? w_de : w_en; // (256, 256)
  const int rowBase = blockIdx.y * 64;   // global row in (B*T)
  const int colBase = blockIdx.x * 32;   // col in U
  __shared__ float Bs[256][32];          // full-K W panel, 32KB
  const int tid = threadIdx.x;           // 0..511
  const int tx = tid & 15, ty = tid >> 4;  // cols tx*2.., rows ty*2.. (ty 0..31)

  // Stage W panel once: thread (r = tid>>1, half = tid&1) loads 16 floats.
  {
    const int r = tid >> 1, h = (tid & 1) * 16;
#pragma unroll
    for (int j = 0; j < 4; ++j)
      *(float4*)&Bs[r][h + j * 4] =
          *(const float4*)&W[(size_t)r * U_ + colBase + h + j * 4];
  }
  __syncthreads();

  float acc[2][2] = {};
#pragma unroll 4
  for (int k4 = 0; k4 < 64; ++k4) {
    float a0[4], a1[4];
    *(float4*)a0 = *(const float4*)&A[(size_t)(rowBase + ty * 2 + 0) * D_ + k4 * 4];
    *(float4*)a1 = *(const float4*)&A[(size_t)(rowBase + ty * 2 + 1) * D_ + k4 * 4];
#pragma unroll
    for (int kk = 0; kk < 4; ++kk) {
      float b[2];
      *(float2*)b = *(const float2*)&Bs[k4 * 4 + kk][tx * 2];
      acc[0][0] = fmaf(a0[kk], b[0], acc[0][0]);
      acc[0][1] = fmaf(a0[kk], b[1], acc[0][1]);
      acc[1][0] = fmaf(a1[kk], b[0], acc[1][0]);
      acc[1][1] = fmaf(a1[kk], b[1], acc[1][1]);
    }
  }

  if (which) {
    // Ed: direct row-major float2 store (128B contiguous per ty-group).
#pragma unroll
    for (int i = 0; i < 2; ++i) {
      float2 o;
      o.x = fexp2(acc[i][0] * TWO_LOG2E_F);
      o.y = fexp2(acc[i][1] * TWO_LOG2E_F);
      *(float2*)&edp[(size_t)(rowBase + ty * 2 + i) * U_ + colBase + tx * 2] = o;
    }
  } else {
    // EeT interleaved: transpose via LDS (reuse Bs; need 32*69=2208 floats).
    __syncthreads();  // all ds_reads of Bs done before overwrite
    float* Cs = &Bs[0][0];
#pragma unroll
    for (int i = 0; i < 2; ++i)
#pragma unroll
      for (int j = 0; j < 2; ++j)
        Cs[(tx * 2 + j) * 69 + ty * 2 + i] = fexp2(acc[i][j] * TWO_LOG2E_F);
    __syncthreads();
    const int b = rowBase >> 8, t0 = rowBase & 255;
    const int u4Base = colBase >> 2;
    const int u4l = tid >> 6, tl = tid & 63;  // 8 u4-groups x 64 t
    float4 v;
    v.x = Cs[(u4l * 4 + 0) * 69 + tl];
    v.y = Cs[(u4l * 4 + 1) * 69 + tl];
    v.z = Cs[(u4l * 4 + 2) * 69 + tl];
    v.w = Cs[(u4l * 4 + 3) * 69 + tl];
    *(float4*)&eet[(size_t)((b * 64 + u4Base + u4l) * 256 + t0 + tl) * 4] = v;
  }
}

// ---------------------------------------------------------------------------
// K24 v4 (fused K2+K4): 8 s-rows/block, 4 per thread. grid 256 = 1 block/CU
// (perfect balance, no tail), 512 threads = 2 waves/SIMD (enough to saturate
// the trans pipe: 16 rcp x 8cy per iter vs ~56 issue cy per wave).
//   Per u-iter: ONE Ee float4 amortized over 16 rcp (2x R6), nu + 4 Ed rows
//   via wave-uniform SGPR loads. Ee L2 traffic halved (64MB); b = id&7 keeps
//   each XCD's L2 serving a single b panel.
// Softmax + t-phase: proven half-split structure widened to 8 rows.
// ---------------------------------------------------------------------------
__global__ __launch_bounds__(512) void coatt_k24(
    const float* __restrict__ en, const float* __restrict__ de,
    const float* __restrict__ nu, const float* __restrict__ eet,
    const float* __restrict__ edp, float* __restrict__ maxmu,
    float* __restrict__ out) {
  const int id = blockIdx.x;
  const int b = id & 7;             // XCD-aligned under round-robin dispatch
  const int sBase = (id >> 3) * 8;  // 8 s-rows per block
  const int tid = threadIdx.x;      // 0..511
  const int t = tid & 255;
  const int half = tid >> 8;        // 0/1 -> local s rows {0..3} / {4..7}
  const int w = tid >> 6, lane = tid & 63;

  __shared__ float als[8][256];   // alphas
  __shared__ float tp[2][8][256]; // t-phase partials [half][s][d]
  __shared__ float part[4][8];    // softmax partials [s-local-in-half][wave]

  // Wave-uniform Ed row base -> SGPR (readfirstlane). half is wave-uniform.
  const int edBase =
      __builtin_amdgcn_readfirstlane((b * TD_ + sBase + half * 4) * U_);
  const float* __restrict__ Ed0 = edp + edBase;        // uniform -> s_load
  const float* __restrict__ Ee_b = eet + (size_t)b * (U_ * TE_) + t * 4;

  float acc0 = 0.f, acc1 = 0.f, acc2 = 0.f, acc3 = 0.f;  // 1 chain per s-row
#pragma unroll 4
  for (int u4 = 0; u4 < 64; ++u4) {
    const float4 ee4 = *(const float4*)&Ee_b[u4 * 1024];   // coalesced 16B
    const float4 nv = *(const float4*)&nu[u4 * 4];         // uniform -> SGPR
    const float4 d0 = *(const float4*)&Ed0[0 * U_ + u4 * 4];
    const float4 d1 = *(const float4*)&Ed0[1 * U_ + u4 * 4];
    const float4 d2 = *(const float4*)&Ed0[2 * U_ + u4 * 4];
    const float4 d3 = *(const float4*)&Ed0[3 * U_ + u4 * 4];
    const float* eep = (const float*)&ee4;
    const float* nvp = (const float*)&nv;
    const float* p0 = (const float*)&d0;
    const float* p1 = (const float*)&d1;
    const float* p2 = (const float*)&d2;
    const float* p3 = (const float*)&d3;
#pragma unroll
    for (int j = 0; j < 4; ++j) {
      acc0 = fmaf(nvp[j], frcp(fmaf(p0[j], eep[j], 1.0f)), acc0);
      acc1 = fmaf(nvp[j], frcp(fmaf(p1[j], eep[j], 1.0f)), acc1);
      acc2 = fmaf(nvp[j], frcp(fmaf(p2[j], eep[j], 1.0f)), acc2);
      acc3 = fmaf(nvp[j], frcp(fmaf(p3[j], eep[j], 1.0f)), acc3);
    }
  }
  float v[4] = {-2.f * acc0, -2.f * acc1, -2.f * acc2, -2.f * acc3};

  // Softmax over t for the 4 local s-rows; each half's 4 waves cover 256 t.
  float m[4];
#pragma unroll
  for (int s = 0; s < 4; ++s) {
    m[s] = v[s];
#pragma unroll
    for (int off = 32; off > 0; off >>= 1)
      m[s] = fmaxf(m[s], __shfl_xor(m[s], off));
    if (lane == 0) part[s][w] = m[s];
  }
  __syncthreads();
  const int wb = half * 4;
#pragma unroll
  for (int s = 0; s < 4; ++s)
    m[s] = fmaxf(fmaxf(part[s][wb], part[s][wb + 1]),
                 fmaxf(part[s][wb + 2], part[s][wb + 3]));
  __syncthreads();
  float e[4], smv[4];
#pragma unroll
  for (int s = 0; s < 4; ++s) {
    e[s] = fexp2((v[s] - m[s]) * LOG2E_F);
    smv[s] = e[s];
#pragma unroll
    for (int off = 32; off > 0; off >>= 1) smv[s] += __shfl_xor(smv[s], off);
    if (lane == 0) part[s][w] = smv[s];
  }
  __syncthreads();
#pragma unroll
  for (int s = 0; s < 4; ++s) {
    const float tot = (part[s][wb] + part[s][wb + 1]) +
                      (part[s][wb + 2] + part[s][wb + 3]);
    als[half * 4 + s][t] = e[s] * frcp(tot);
  }
  if (t == 0) {
#pragma unroll
    for (int s = 0; s < 4; ++s)
      maxmu[b * TD_ + sBase + half * 4 + s] = m[s];
  }
  __syncthreads();

  // Phase t: d = t; halves cover disjoint t-ranges for ALL 8 s-rows.
  const int d = t;
  const int tBeg = half * 128;
  const float* __restrict__ en_b = en + (size_t)b * TE_ * D_ + d;
  float sa[8] = {};
#pragma unroll 2
  for (int t4 = 0; t4 < 32; ++t4) {
    const int tt = tBeg + t4 * 4;
    float env[4];
#pragma unroll
    for (int j = 0; j < 4; ++j) env[j] = en_b[(size_t)(tt + j) * D_];  // coalesced
#pragma unroll
    for (int s = 0; s < 8; ++s) {
      const float4 a = *(const float4*)&als[s][tt];  // LDS broadcast
      const float* q = (const float*)&a;
#pragma unroll
      for (int j = 0; j < 4; ++j) sa[s] = fmaf(q[j], env[j], sa[s]);
    }
  }
#pragma unroll
  for (int s = 0; s < 8; ++s) tp[half][s][d] = sa[s];
  __syncthreads();
#pragma unroll
  for (int k = 0; k < 4; ++k) {
    const int sl = half * 4 + k;
    const float se = tp[0][sl][d] + tp[1][sl][d];
    const int s = sBase + sl;
    const float dd = de[(size_t)(b * TD_ + s) * D_ + d];
    float* o = out + (size_t)(b * TD_ + s) * (4 * D_);
    o[d] = dd;
    o[D_ + d] = se;
    o[2 * D_ + d] = dd * se;
  }
}

// ---------------------------------------------------------------------------
// K3 (IDENTICAL to R6): max_alphas = softmax_s(maxmu[b,:]); h_hat; out chunk 3.
// grid (8, 8), 256 threads.
// ---------------------------------------------------------------------------
__global__ __launch_bounds__(256) void coatt_k3_hhat(
    const float* __restrict__ de, const float* __restrict__ maxmu,
    float* __restrict__ out) {
  const int b = blockIdx.y;
  const int dBase = blockIdx.x * 32;
  const int tid = threadIdx.x;
  const int w = tid >> 6, lane = tid & 63;
  __shared__ float red[8];
  __shared__ float malpha[256];
  __shared__ float acc_red[256];
  __shared__ float hh_s[32];
  const float vv = maxmu[b * TD_ + tid];
  float m = vv;
#pragma unroll
  for (int off = 32; off > 0; off >>= 1) m = fmaxf(m, __shfl_xor(m, off));
  if (lane == 0) red[w] = m;
  __syncthreads();
  m = fmaxf(fmaxf(red[0], red[1]), fmaxf(red[2], red[3]));
  const float e = fexp2((vv - m) * LOG2E_F);
  float sm = e;
#pragma unroll
  for (int off = 32; off > 0; off >>= 1) sm += __shfl_xor(sm, off);
  if (lane == 0) red[4 + w] = sm;
  __syncthreads();
  sm = (red[4] + red[5]) + (red[6] + red[7]);
  malpha[tid] = e * frcp(sm);
  __syncthreads();
  const int dl = tid & 31, sg = tid >> 5;
  float acc = 0.f;
  for (int s = sg * 32; s < sg * 32 + 32; ++s)
    acc = fmaf(de[(size_t)(b * TD_ + s) * D_ + dBase + dl], malpha[s], acc);
  acc_red[tid] = acc;
  __syncthreads();
  if (tid < 32) {
    float tsum = acc_red[tid];
#pragma unroll
    for (int g = 1; g < 8; ++g) tsum += acc_red[g * 32 + tid];
    hh_s[tid] = tsum;
  }
  __syncthreads();
  const float hh = hh_s[dl];
#pragma unroll 4
  for (int s = sg; s < TD_; s += 8) {
    const float dd = de[(size_t)(b * TD_ + s) * D_ + dBase + dl];
    out[(size_t)(b * TD_ + s) * (4 * D_) + 3 * D_ + dBase + dl] = dd * hh;
  }
}

extern "C" void kernel_launch(void* const* d_in, const int* in_sizes, int n_in,
                              void* d_out, int out_size, void* d_ws, size_t ws_size,
                              hipStream_t stream) {
  (void)in_sizes; (void)n_in; (void)out_size; (void)ws_size;
  const float* en   = (const float*)d_in[0];
  const float* de   = (const float*)d_in[1];
  const float* w_en = (const float*)d_in[2];
  const float* w_de = (const float*)d_in[3];
  const float* nu   = (const float*)d_in[4];
  float* out = (float*)d_out;
  float* ws  = (float*)d_ws;

  coatt_k1_proj<<<dim3(8, 32, 2), 512, 0, stream>>>(
      en, de, w_en, w_de, ws + EET_OFF, ws + ED_OFF);
  coatt_k24<<<dim3(256), 512, 0, stream>>>(
      en, de, nu, ws + EET_OFF, ws + ED_OFF, ws + MAXMU_OFF, out);
  coatt_k3_hhat<<<dim3(8, 8), 256, 0, stream>>>(de, ws + MAXMU_OFF, out);
}